// Round 8
// baseline (103.825 us; speedup 1.0000x reference)
//
#include <hip/hip_runtime.h>
#include <hip/hip_bf16.h>

#define NH 8
#define HID 64
#define NPAIRS (16 * 256 * 256)
#define BLOCK 256
#define LROWD 36   // dwords per LDS row (32 data + 4 pad) = 144 B, 16B-aligned

typedef __attribute__((ext_vector_type(8))) short bf16x8;
typedef __attribute__((ext_vector_type(4))) float f32x4;
typedef __attribute__((ext_vector_type(16))) float f32x16;

union F8 { bf16x8 v; unsigned u[4]; uint4 q4; };

// f32 pair -> packed bf16 dword (RNE, a in low half) via HW v_cvt_pk_bf16_f32
__device__ inline unsigned pk2(float a, float b) {
    __hip_bfloat162 h = __float22bfloat162_rn(make_float2(a, b));
    unsigned u;
    __builtin_memcpy(&u, &h, 4);
    return u;
}

// Hidden-dim storage permutation: LDS/bf16 position j holds hid H(j).
// j even -> h = j/2 (GEMM1 half m=0), j odd -> h = 32 + j/2 (half m=1).
__device__ inline int Hperm(int j) { return (j & 1) * 32 + (j >> 1); }

// ws layout (bytes):
//   0    : B1 frags [m=0,1][lane] x16B — W1 in 32x32x16 B-layout, K row 12 = b1 (bias-as-feature)
//   2048 : B2 frags [kc=0,1][lane] x16B — W2 rows permuted by Hperm, 16x16x32 B-layout
//   4096 : b2v [lane] f32 — (lane&15)<8 ? b2[lane&15] : 0
__global__ void pack_weights(const float* __restrict__ W1, const float* __restrict__ b1,
                             const float* __restrict__ W2, const float* __restrict__ b2,
                             unsigned char* __restrict__ ws) {
    int l = threadIdx.x;               // 0..63
    int n32 = l & 31, q2 = l >> 5;
    int n16 = l & 15, q4 = l >> 4;
    unsigned* B1 = (unsigned*)ws;
    unsigned* B2 = (unsigned*)(ws + 2048);
    float* b2v = (float*)(ws + 4096);
    // 32x32x16 B-layout: lane holds B[k = q2*8 + j][n = l&31]; k=12 row carries b1
    for (int m = 0; m < 2; ++m) {
        int h = m * 32 + n32;
        for (int j2 = 0; j2 < 4; ++j2) {
            int k0 = q2 * 8 + 2 * j2, k1 = k0 + 1;
            float v0 = (k0 < 12) ? W1[k0 * HID + h] : (k0 == 12 ? b1[h] : 0.f);
            float v1 = (k1 < 12) ? W1[k1 * HID + h] : 0.f;
            B1[(m * 64 + l) * 4 + j2] = pk2(v0, v1);
        }
    }
    // 16x16x32 B-layout with Hperm on k: lane holds B[k][n16], k = kc*32 + q4*8 + j
    for (int kc = 0; kc < 2; ++kc)
        for (int j2 = 0; j2 < 4; ++j2) {
            int k0 = kc * 32 + q4 * 8 + 2 * j2;
            float v0 = (n16 < NH) ? W2[Hperm(k0) * NH + n16] : 0.f;
            float v1 = (n16 < NH) ? W2[Hperm(k0 + 1) * NH + n16] : 0.f;
            B2[(kc * 64 + l) * 4 + j2] = pk2(v0, v1);
        }
    b2v[l] = (n16 < NH) ? b2[n16] : 0.f;
}

__global__ __launch_bounds__(BLOCK) void relfeat_mfma4(
    const float* __restrict__ ff, const unsigned char* __restrict__ ws,
    float* __restrict__ out)
{
    __shared__ unsigned lds[4][32 * LROWD];   // 18432 B/block -> 8 blocks/CU
    const int tid = threadIdx.x;
    const int w = tid >> 6, l = tid & 63;
    const int n32 = l & 31, q2 = l >> 5;
    const int n16 = l & 15, q4 = l >> 4;
    unsigned* my = lds[w];                    // per-wave private, no barriers

    F8 B1f[2], B2f[2];
    B1f[0].q4 = ((const uint4*)ws)[l];
    B1f[1].q4 = ((const uint4*)ws)[64 + l];
    B2f[0].q4 = ((const uint4*)(ws + 2048))[l];
    B2f[1].q4 = ((const uint4*)(ws + 2048))[64 + l];
    const float b2s = ((const float*)(ws + 4096))[l];

    f32x16 z16;
    #pragma unroll
    for (int r = 0; r < 16; ++r) z16[r] = 0.f;

    const int wave_base = (blockIdx.x * 4 + w) * 128;

    #pragma unroll
    for (int it = 0; it < 2; ++it) {
        const int pbase = wave_base + it * 64;

        // ---- each lane computes ITS OWN pair (pbase + l) fully ----
        float4 v = ((const float4*)ff)[pbase + l];
        float rx = v.x, ry = v.y, rvx = v.z, rvy = v.w;
        float dist_sq = rx * rx + ry * ry;
        float invd = __builtin_amdgcn_rsqf(dist_sq + 1e-6f);   // ~ 1/(dist+1e-6)
        float dist = (dist_sq + 1e-6f) * invd;                 // = sqrt(dist_sq+1e-6)
        float speed_sq = rvx * rvx + rvy * rvy;
        float dot_vp = rvx * rx + rvy * ry;
        float inv_dist = __builtin_amdgcn_rcpf(dist + 0.1f);
        float rel_speed = sqrtf(speed_sq + 1e-6f);
        float closing = dot_vp * invd;
        float dir_x = rx * invd, dir_y = ry * invd;
        float zz = -dot_vp * __builtin_amdgcn_rcpf(speed_sq + 1e-6f);
        float ez = __expf(2.f * zz);
        float ttca = 1.f - 2.f * __builtin_amdgcn_rcpf(ez + 1.f);   // tanh(zz)

        unsigned c0 = pk2(rx, ry), c1 = pk2(rvx, rvy);
        unsigned c2 = pk2(dist, inv_dist), c3 = pk2(rel_speed, closing);
        unsigned c4 = pk2(dir_x, dir_y), c5 = pk2(ttca, dot_vp);
        unsigned sw0 = (unsigned)__shfl_xor((int)c0, 32);
        unsigned sw1 = (unsigned)__shfl_xor((int)c1, 32);
        unsigned sw2 = (unsigned)__shfl_xor((int)c2, 32);
        unsigned sw3 = (unsigned)__shfl_xor((int)c3, 32);
        unsigned sw4 = (unsigned)__shfl_xor((int)c4, 32);
        unsigned sw5 = (unsigned)__shfl_xor((int)c5, 32);

        // A1 frags (32x32x16, HW-verified): A[m = l&31][k = q2*8 + j]
        const bool hi = (q2 != 0);
        F8 frag[2];
        frag[0].u[0] = hi ? sw4 : c0;
        frag[0].u[1] = hi ? sw5 : c1;
        frag[0].u[2] = hi ? 0x00003f80u : c2;    // k12 = 1.0 (bias feature)
        frag[0].u[3] = hi ? 0u : c3;
        frag[1].u[0] = hi ? c4 : sw0;
        frag[1].u[1] = hi ? c5 : sw1;
        frag[1].u[2] = hi ? 0x00003f80u : sw2;
        frag[1].u[3] = hi ? 0u : sw3;

        #pragma unroll
        for (int G = 0; G < 2; ++G) {
            const int pg = pbase + G * 32;

            // GEMM1: both hid halves up front
            f32x16 d1a = __builtin_amdgcn_mfma_f32_32x32x16_bf16(frag[G].v, B1f[0].v, z16, 0, 0, 0);
            f32x16 d1b = __builtin_amdgcn_mfma_f32_32x32x16_bf16(frag[G].v, B1f[1].v, z16, 0, 0, 0);

            // silu + interleaved pack: one cvt_pk + one aligned ds_write_b32 per r
            // C/D 32x32: col(hid_local) = n32, row(pair) = (r&3)+8*(r>>2)+4*q2
            #pragma unroll
            for (int r = 0; r < 16; ++r) {
                int prow = (r & 3) + 8 * (r >> 2) + 4 * q2;
                float x0 = d1a[r], x1 = d1b[r];
                float s0 = x0 * __builtin_amdgcn_rcpf(1.f + __expf(-x0));
                float s1 = x1 * __builtin_amdgcn_rcpf(1.f + __expf(-x1));
                my[prow * LROWD + n32] = pk2(s0, s1);   // positions 2*n32, 2*n32+1
            }

            // GEMM2: A2 frag = one ds_read_b128 (8 consecutive bf16 positions)
            #pragma unroll
            for (int hl = 0; hl < 2; ++hl) {
                f32x4 d2 = {b2s, b2s, b2s, b2s};
                #pragma unroll
                for (int kc = 0; kc < 2; ++kc) {
                    F8 a2;
                    a2.q4 = *(const uint4*)((const unsigned char*)my
                              + (hl * 16 + n16) * (LROWD * 4) + kc * 64 + q4 * 16);
                    d2 = __builtin_amdgcn_mfma_f32_16x16x32_bf16(a2.v, B2f[kc].v, d2, 0, 0, 0);
                }
                if (n16 < NH) {
                    int p0 = pg + hl * 16 + q4 * 4;
                    int b = p0 >> 16, lo16 = p0 & 65535;
                    float4 st; st.x = d2[0]; st.y = d2[1]; st.z = d2[2]; st.w = d2[3];
                    *(float4*)(out + (size_t)b * (NH * 65536) + (size_t)n16 * 65536 + lo16) = st;
                }
            }
        }
    }
}

extern "C" void kernel_launch(void* const* d_in, const int* in_sizes, int n_in,
                              void* d_out, int out_size, void* d_ws, size_t ws_size,
                              hipStream_t stream) {
    const float* ff = (const float*)d_in[0];
    const float* W1 = (const float*)d_in[1];
    const float* b1 = (const float*)d_in[2];
    const float* W2 = (const float*)d_in[3];
    const float* b2 = (const float*)d_in[4];
    float* out = (float*)d_out;
    unsigned char* ws = (unsigned char*)d_ws;   // 4352 bytes used

    pack_weights<<<1, 64, 0, stream>>>(W1, b1, W2, b2, ws);
    const int grid = NPAIRS / (128 * 4);        // 2048 blocks, 4 waves x 128 pairs
    relfeat_mfma4<<<grid, BLOCK, 0, stream>>>(ff, ws, out);
}

// Round 10
// 102.581 us; speedup vs baseline: 1.0121x; 1.0121x over previous
//
#include <hip/hip_runtime.h>
#include <hip/hip_bf16.h>

#define NH 8
#define HID 64
#define NPAIRS (16 * 256 * 256)
#define BLOCK 256

typedef __attribute__((ext_vector_type(8))) short bf16x8;
typedef __attribute__((ext_vector_type(16))) float f32x16;

union F8 { bf16x8 v; unsigned u[4]; uint4 q4; };

// f32 pair -> packed bf16 dword (RNE, a in low half) via HW v_cvt_pk_bf16_f32
__device__ inline unsigned pk2(float a, float b) {
    __hip_bfloat162 h = __float22bfloat162_rn(make_float2(a, b));
    unsigned u;
    __builtin_memcpy(&u, &h, 4);
    return u;
}

// Swap bits 2<->3: maps D1 C-row m -> logical hidden unit, chosen so each
// lane's D1 registers are exactly the GEMM2 B-frag dwords it supplies
// (no cross-lane exchange needed). Applied to W1 columns; W2 indexing
// already uses logical hid, so it needs no change.
__device__ inline int hperm(int m) {
    return (m & 0x13) | ((m & 8) >> 1) | ((m & 4) << 1);
}

// Single fused kernel. No LDS, no workspace, no pack kernel, no GEMM2 shfl.
// GEMM1 (swapped operands): D1[hid][pair] = mfma32(A=W1t_perm, B=F)
// GEMM2: D2[out][pair] = sum_kc mfma32(A=W2t[kc], B=silu(D1) own-reg frags)
__global__ __launch_bounds__(BLOCK) void relfeat_mfma6(
    const float* __restrict__ ff, const float* __restrict__ W1,
    const float* __restrict__ b1, const float* __restrict__ W2,
    const float* __restrict__ b2, float* __restrict__ out)
{
    const int tid = threadIdx.x;
    const int w = tid >> 6, l = tid & 63;
    const int n32 = l & 31, q2 = l >> 5;

    // ---- per-wave weight fragment pack (cached global loads, once) ----
    // B1f[mh] as A-operand: A[m_row = l&31][k = feat = q2*8+j]; row m holds
    // logical hid h = 32*mh + hperm(m); k=12 row carries b1 (bias-as-feature).
    F8 B1f[2];
    #pragma unroll
    for (int mh = 0; mh < 2; ++mh) {
        int h = 32 * mh + hperm(n32);
        #pragma unroll
        for (int j2 = 0; j2 < 4; ++j2) {
            int k0 = q2 * 8 + 2 * j2, k1 = k0 + 1;
            float v0 = (k0 < 12) ? W1[k0 * HID + h] : (k0 == 12 ? b1[h] : 0.f);
            float v1 = (k1 < 12) ? W1[k1 * HID + h] : 0.f;
            B1f[mh].u[j2] = pk2(v0, v1);
        }
    }
    // W2A[kc] as A-operand of GEMM2: A[m_row = out = l&31 (<8 real)][k],
    // value = W2[logical hid = 16kc + q2*8 + j][out]
    F8 W2A[4];
    #pragma unroll
    for (int kc = 0; kc < 4; ++kc) {
        #pragma unroll
        for (int j2 = 0; j2 < 4; ++j2) {
            int hid = 16 * kc + q2 * 8 + 2 * j2;
            float v0 = (n32 < NH) ? W2[hid * NH + n32] : 0.f;
            float v1 = (n32 < NH) ? W2[(hid + 1) * NH + n32] : 0.f;
            W2A[kc].u[j2] = pk2(v0, v1);
        }
    }
    float b2r[4];
    #pragma unroll
    for (int r = 0; r < 4; ++r) b2r[r] = b2[r + 4 * q2];   // out = r + 4*q2

    f32x16 z16;
    #pragma unroll
    for (int r = 0; r < 16; ++r) z16[r] = 0.f;

    const int wave_base = (blockIdx.x * 4 + w) * 128;

    #pragma unroll
    for (int it = 0; it < 2; ++it) {
        const int pbase = wave_base + it * 64;

        // ---- each lane computes ITS OWN pair (pbase + l) fully ----
        float4 v = ((const float4*)ff)[pbase + l];
        float rx = v.x, ry = v.y, rvx = v.z, rvy = v.w;
        float dist_sq = rx * rx + ry * ry;
        float invd = __builtin_amdgcn_rsqf(dist_sq + 1e-6f);    // ~ 1/(dist+1e-6)
        float dist = (dist_sq + 1e-6f) * invd;                  // sqrt(dist_sq+1e-6)
        float speed_sq = rvx * rvx + rvy * rvy;
        float dot_vp = rvx * rx + rvy * ry;
        float inv_dist = __builtin_amdgcn_rcpf(dist + 0.1f);
        float rel_speed = sqrtf(speed_sq + 1e-6f);
        float closing = dot_vp * invd;
        float dir_x = rx * invd, dir_y = ry * invd;
        float zz = -dot_vp * __builtin_amdgcn_rcpf(speed_sq + 1e-6f);
        float ez = __expf(2.f * zz);
        float ttca = 1.f - 2.f * __builtin_amdgcn_rcpf(ez + 1.f);   // tanh(zz)

        unsigned c0 = pk2(rx, ry), c1 = pk2(rvx, rvy);
        unsigned c2 = pk2(dist, inv_dist), c3 = pk2(rel_speed, closing);
        unsigned c4 = pk2(dir_x, dir_y), c5 = pk2(ttca, dot_vp);
        // feature exchange (R7/R8-proven pattern)
        unsigned sw0 = (unsigned)__shfl_xor((int)c0, 32);
        unsigned sw1 = (unsigned)__shfl_xor((int)c1, 32);
        unsigned sw2 = (unsigned)__shfl_xor((int)c2, 32);
        unsigned sw3 = (unsigned)__shfl_xor((int)c3, 32);
        unsigned sw4 = (unsigned)__shfl_xor((int)c4, 32);
        unsigned sw5 = (unsigned)__shfl_xor((int)c5, 32);

        // Feature B-frags: B[k = feat = q2*8 + j][n = pair = l&31]
        const bool hi = (q2 != 0);
        F8 frag[2];
        frag[0].u[0] = hi ? sw4 : c0;
        frag[0].u[1] = hi ? sw5 : c1;
        frag[0].u[2] = hi ? 0x00003f80u : c2;    // k12 = 1.0 (bias feature)
        frag[0].u[3] = hi ? 0u : c3;
        frag[1].u[0] = hi ? c4 : sw0;
        frag[1].u[1] = hi ? c5 : sw1;
        frag[1].u[2] = hi ? 0x00003f80u : sw2;
        frag[1].u[3] = hi ? 0u : sw3;

        #pragma unroll
        for (int G = 0; G < 2; ++G) {
            const int pg = pbase + G * 32;

            // GEMM1 swapped: D1[hid][pair]; d1a = logical hid 0..31, d1b = 32..63
            f32x16 d1a = __builtin_amdgcn_mfma_f32_32x32x16_bf16(B1f[0].v, frag[G].v, z16, 0, 0, 0);
            f32x16 d1b = __builtin_amdgcn_mfma_f32_32x32x16_bf16(B1f[1].v, frag[G].v, z16, 0, 0, 0);

            // GEMM2: 4 chained mfma; B-frag = silu of OWN regs (hperm makes
            // reg r of half mh == k-slot j=r&7 of block kc = 2*mh + (r>>3))
            f32x16 d2 = z16;
            #pragma unroll
            for (int kc = 0; kc < 4; ++kc) {
                const f32x16& d1 = (kc < 2) ? d1a : d1b;
                const int rb = (kc & 1) * 8;
                float s[8];
                #pragma unroll
                for (int j = 0; j < 8; ++j) {
                    float x = d1[rb + j];
                    s[j] = x * __builtin_amdgcn_rcpf(1.f + __expf(-x));
                }
                F8 bf;
                bf.u[0] = pk2(s[0], s[1]);
                bf.u[1] = pk2(s[2], s[3]);
                bf.u[2] = pk2(s[4], s[5]);
                bf.u[3] = pk2(s[6], s[7]);
                d2 = __builtin_amdgcn_mfma_f32_32x32x16_bf16(W2A[kc].v, bf.v, d2, 0, 0, 0);
            }

            // D2 C-layout: col = pair = l&31; row = out = (r&3)+8*(r>>2)+4*q2.
            // Outs 0..7 live in regs 0..3 (q2 selects low/high 4). All lanes store.
            int b = pg >> 16, lo16 = pg & 65535;
            float* op = out + (size_t)b * (NH * 65536) + lo16 + n32;
            #pragma unroll
            for (int r = 0; r < 4; ++r) {
                op[(size_t)(r + 4 * q2) * 65536] = d2[r] + b2r[r];
            }
        }
    }
}

extern "C" void kernel_launch(void* const* d_in, const int* in_sizes, int n_in,
                              void* d_out, int out_size, void* d_ws, size_t ws_size,
                              hipStream_t stream) {
    const float* ff = (const float*)d_in[0];
    const float* W1 = (const float*)d_in[1];
    const float* b1 = (const float*)d_in[2];
    const float* W2 = (const float*)d_in[3];
    const float* b2 = (const float*)d_in[4];
    float* out = (float*)d_out;

    const int grid = NPAIRS / (128 * 4);   // 2048 blocks, 4 waves x 128 pairs each
    relfeat_mfma6<<<grid, BLOCK, 0, stream>>>(ff, W1, b1, W2, b2, out);
}